// Round 1
// baseline (150.225 us; speedup 1.0000x reference)
//
#include <hip/hip_runtime.h>
#include <math.h>

#define IMG_H 512
#define IMG_W 512
#define NSLOT 64
#define HT_S  56      // hT stride in halves: 112 B rows, 16B-aligned

typedef _Float16 f16x4 __attribute__((ext_vector_type(4)));
typedef _Float16 f16x8 __attribute__((ext_vector_type(8)));
typedef float    f32x4 __attribute__((ext_vector_type(4)));

// Zero-padded 11-tap Gaussian (sigma=1.5), f16, normalized (1/sum = 0.26601173).
// Index domain: idx in [-18, 33] -> WPAD[idx + 18]. Nonzero only for idx in [0,10].
// Values = 0.26601173 * exp(-(idx-5)^2 / 4.5), identical to the old exp2f formula.
__device__ const _Float16 WPAD[52] = {
    (_Float16)0.f,(_Float16)0.f,(_Float16)0.f,(_Float16)0.f,(_Float16)0.f,(_Float16)0.f,
    (_Float16)0.f,(_Float16)0.f,(_Float16)0.f,(_Float16)0.f,(_Float16)0.f,(_Float16)0.f,
    (_Float16)0.f,(_Float16)0.f,(_Float16)0.f,(_Float16)0.f,(_Float16)0.f,(_Float16)0.f,   // idx -18..-1
    (_Float16)0.00102838f, (_Float16)0.00759876f, (_Float16)0.03600077f,
    (_Float16)0.10936065f, (_Float16)0.21300554f, (_Float16)0.26601173f,
    (_Float16)0.21300554f, (_Float16)0.10936065f, (_Float16)0.03600077f,
    (_Float16)0.00759876f, (_Float16)0.00102838f,                                          // idx 0..10
    (_Float16)0.f,(_Float16)0.f,(_Float16)0.f,(_Float16)0.f,(_Float16)0.f,(_Float16)0.f,
    (_Float16)0.f,(_Float16)0.f,(_Float16)0.f,(_Float16)0.f,(_Float16)0.f,(_Float16)0.f,
    (_Float16)0.f,(_Float16)0.f,(_Float16)0.f,(_Float16)0.f,(_Float16)0.f,(_Float16)0.f,
    (_Float16)0.f,(_Float16)0.f,(_Float16)0.f,(_Float16)0.f,(_Float16)0.f                  // idx 11..33
};

// 8 consecutive f16 table entries starting at (padded) index `base`.
__device__ __forceinline__ f16x8 frag_from_tab(int base)
{
    f16x8 f;
    #pragma unroll
    for (int j = 0; j < 8; ++j) f[j] = WPAD[base + j];
    return f;
}

__global__ __launch_bounds__(256, 8)
void ssim_main(const float* __restrict__ pred, const float* __restrict__ targ,
               float* __restrict__ partial, double* __restrict__ acc, int mode)
{
    __shared__ _Float16 hT[4][32][HT_S];     // [q][out_col][halo_row 0..47]

    const int tid  = threadIdx.x;
    const int lane = tid & 63, wave = tid >> 6;
    const int ln   = lane & 15, lg = lane >> 4;

    // XCD swizzle: 8 XCDs, grid % 8 == 0 (nwg = n_img*256). Give each XCD a
    // contiguous chunk (= whole image planes) so halo re-reads stay in one L2.
    const int bid   = ((blockIdx.z << 4) + blockIdx.y) * 16 + blockIdx.x;
    const int chunk = (int)gridDim.z << 5;            // nwg/8 = n_img*256/8
    const int nb    = (bid & 7) * chunk + (bid >> 3);
    const int img   = nb >> 8;
    const int rem   = nb & 255;
    const int ty    = rem >> 4, tx = rem & 15;

    const float* __restrict__ p = pred + (size_t)img * (IMG_H * IMG_W);
    const float* __restrict__ t = targ + (size_t)img * (IMG_H * IMG_W);
    const int gr0 = ty * 32 - 5;       // halo row 0 (global)
    const int wo  = tx * 32 - 8;       // halo col 0 (global)

    // Banded Gaussian fragments from table (loads, not exp2):
    // Bw:  B[k][n] = w[k-n-3]  -> WPAD[18 + lg*8+j - ln - 3]
    const f16x8 Bw = frag_from_tab(15 + lg * 8 - ln);
    const f32x4 z = {0.f, 0.f, 0.f, 0.f};

    // ---- Fused stage A+B: global->regs, horizontal conv via MFMA on {s,d,s^2,d^2} ----
    // 6 tiles: rt in {0,1,2} x ct in {0,1}; wave w does tile w; waves 0,1 also do 4,5.
    auto do_tile = [&](int tt) {
        const int rt = tt >> 1, ct = tt & 1;
        const int rowbase = rt * 16;
        const int gr = gr0 + rowbase + ln;           // global row (A-frag row = ln)
        const int gc = wo + ct * 16 + lg * 8;        // global col of this lane's 8 elems
        const bool in = (gr >= 0) && (gr < IMG_H) &&
                        !(tx == 0 && ct == 0 && lg == 0) &&
                        !(tx == 15 && ct == 1 && lg == 3);
        float4 p0 = {0,0,0,0}, p1 = {0,0,0,0}, t0 = {0,0,0,0}, t1 = {0,0,0,0};
        if (in) {
            const float* bp = p + (size_t)gr * IMG_W + gc;
            const float* bt = t + (size_t)gr * IMG_W + gc;
            p0 = ((const float4*)bp)[0]; p1 = ((const float4*)bp)[1];
            t0 = ((const float4*)bt)[0]; t1 = ((const float4*)bt)[1];
        }
        f16x8 s8 = f16x8{
            (_Float16)(p0.x + t0.x), (_Float16)(p0.y + t0.y),
            (_Float16)(p0.z + t0.z), (_Float16)(p0.w + t0.w),
            (_Float16)(p1.x + t1.x), (_Float16)(p1.y + t1.y),
            (_Float16)(p1.z + t1.z), (_Float16)(p1.w + t1.w)};
        f16x8 d8 = f16x8{
            (_Float16)(p0.x - t0.x), (_Float16)(p0.y - t0.y),
            (_Float16)(p0.z - t0.z), (_Float16)(p0.w - t0.w),
            (_Float16)(p1.x - t1.x), (_Float16)(p1.y - t1.y),
            (_Float16)(p1.z - t1.z), (_Float16)(p1.w - t1.w)};
        f16x8 fq[4];
        fq[0] = s8; fq[1] = d8;
        fq[2] = s8 * s8; fq[3] = d8 * d8;
        const int ocol = ct * 16 + ln;
        const int orow = rowbase + lg * 4;           // 8B-aligned b64 writes
        #pragma unroll
        for (int q = 0; q < 4; ++q) {
            f32x4 dd = __builtin_amdgcn_mfma_f32_16x16x32_f16(fq[q], Bw, z, 0, 0, 0);
            *(f16x4*)&hT[q][ocol][orow] =
                f16x4{(_Float16)dd[0], (_Float16)dd[1], (_Float16)dd[2], (_Float16)dd[3]};
        }
    };
    do_tile(wave);
    if (wave < 2) do_tile(wave + 4);

    // A2w: A[m][k] = w[k-m] -> WPAD[18 + lg*8+j - ln]; issue loads before barrier.
    const f16x8 A2w = frag_from_tab(18 + lg * 8 - ln);
    __syncthreads();

    // ---- Stage C: vertical conv via MFMA (weights as A) + SSIM ----
    float lsum = 0.f;
    {
        const int ctv = wave & 1, rtv = wave >> 1;   // one 16x16 output tile per wave
        const int ocol  = ctv * 16 + ln;
        const int rbase = rtv * 16 + lg * 8;         // 16B-aligned b128 reads
        f32x4 accq[4];
        #pragma unroll
        for (int q = 0; q < 4; ++q) {
            f16x8 b = *(const f16x8*)&hT[q][ocol][rbase];
            accq[q] = __builtin_amdgcn_mfma_f32_16x16x32_f16(A2w, b, z, 0, 0, 0);
        }
        // F1=conv(s)=mp+mt, F2=conv(d)=mp-mt, F3=conv(s^2), F4=conv(d^2)
        const float C1 = 1e-4f, C2 = 9e-4f;
        #pragma unroll
        for (int r = 0; r < 4; ++r) {
            float F1 = accq[0][r], F2 = accq[1][r];
            float F3 = accq[2][r], F4 = accq[3][r];
            float a = F1 * F1, b = F2 * F2;
            float mpmt2 = 0.5f * (a - b);            // 2*mp*mt
            float msq   = 0.5f * (a + b);            // mp^2 + mt^2
            float cpt2  = 0.5f * (F3 - F4) - mpmt2;  // 2*sigma_pt
            float vsum  = 0.5f * (F3 + F4) - msq;    // sigma_p^2 + sigma_t^2
            float num = (mpmt2 + C1) * (cpt2 + C2);
            float den = (msq + C1) * (vsum + C2);
            lsum = fmaf(num, __builtin_amdgcn_rcpf(den), lsum);
        }
    }

    // ---- wave reduce -> per-wave slot (mode 0) or atomic (mode 1); no end barrier ----
    #pragma unroll
    for (int off = 32; off > 0; off >>= 1)
        lsum += __shfl_down(lsum, off, 64);
    if (lane == 0) {
        if (mode == 0) partial[nb * 4 + wave] = lsum;
        else atomicAdd(&acc[(nb * 4 + wave) & (NSLOT - 1)], (double)lsum);
    }
}

__global__ void ssim_init(double* acc)
{
    if (threadIdx.x < NSLOT) acc[threadIdx.x] = 0.0;
}

__global__ __launch_bounds__(1024)
void ssim_fin_slots(const float* __restrict__ partial, float* __restrict__ out,
                    int n4, double inv_n)
{
    __shared__ double red[16];
    double s = 0.0;
    const int tid = threadIdx.x;
    for (int i = tid; i < n4; i += 1024) {
        float4 v = ((const float4*)partial)[i];
        s += (double)v.x + (double)v.y + (double)v.z + (double)v.w;
    }
    #pragma unroll
    for (int off = 32; off > 0; off >>= 1)
        s += __shfl_down(s, off, 64);
    if ((tid & 63) == 0) red[tid >> 6] = s;
    __syncthreads();
    if (tid == 0) {
        double tot = 0.0;
        #pragma unroll
        for (int w = 0; w < 16; ++w) tot += red[w];
        out[0] = (float)(1.0 - tot * inv_n);
    }
}

__global__ void ssim_fin_atomic(const double* __restrict__ acc, float* __restrict__ out,
                                double inv_n)
{
    if (threadIdx.x == 0) {
        double s = 0.0;
        for (int i = 0; i < NSLOT; ++i) s += acc[i];
        out[0] = (float)(1.0 - s * inv_n);
    }
}

extern "C" void kernel_launch(void* const* d_in, const int* in_sizes, int n_in,
                              void* d_out, int out_size, void* d_ws, size_t ws_size,
                              hipStream_t stream)
{
    const float* pred = (const float*)d_in[0];
    const float* targ = (const float*)d_in[1];
    float* out = (float*)d_out;

    const long long total = (long long)in_sizes[0];       // 16*3*512*512
    const int n_img = (int)(total / (IMG_H * IMG_W));     // 48 planes
    dim3 grid(IMG_W / 32, IMG_H / 32, n_img);
    const int nblk = grid.x * grid.y * grid.z;
    const int nslots = nblk * 4;
    const double inv_n = 1.0 / (double)total;

    if (ws_size >= (size_t)nslots * sizeof(float)) {
        float* partial = (float*)d_ws;
        hipLaunchKernelGGL(ssim_main, grid, dim3(256), 0, stream,
                           pred, targ, partial, (double*)nullptr, 0);
        hipLaunchKernelGGL(ssim_fin_slots, dim3(1), dim3(1024), 0, stream,
                           partial, out, nslots / 4, inv_n);
    } else {
        double* acc = (double*)d_ws;
        hipLaunchKernelGGL(ssim_init, dim3(1), dim3(64), 0, stream, acc);
        hipLaunchKernelGGL(ssim_main, grid, dim3(256), 0, stream,
                           pred, targ, (float*)nullptr, acc, 1);
        hipLaunchKernelGGL(ssim_fin_atomic, dim3(1), dim3(1), 0, stream,
                           acc, out, inv_n);
    }
}